// Round 4
// baseline (139.606 us; speedup 1.0000x reference)
//
#include <hip/hip_runtime.h>
#include <hip/hip_bf16.h>

#define S 16
#define C 8
#define SC 128
#define TT 500
#define NN 1500
#define NF4 375
#define CHUNK 25
#define NCHUNK 20

__device__ __forceinline__ float fexp2(float x) { return exp2f(x); }
__device__ __forceinline__ float flog2(float x) { return log2f(x); }

#define L2E 1.4426950408889634f
#define LN2 0.6931471805599453f

typedef float f4v __attribute__((ext_vector_type(4)));

// ---------------- Kernel 1: all small work, 1 block, 256 threads -----------
#define MM(dst, Asrc, Bsrc) do {                                          \
    __syncthreads();                                                      \
    {   const int c_ = tid >> 5; const int e0_ = tid & 31;                \
        for (int r_ = 0; r_ < 8; ++r_) {                                  \
            const int e_ = e0_ + (r_ << 5);                               \
            const int i_ = e_ >> 4; const int l_ = e_ & 15;               \
            float acc_ = 0.f;                                             \
            _Pragma("unroll")                                             \
            for (int s_ = 0; s_ < S; ++s_)                                \
                acc_ += Asrc[(c_ * S + i_) * S + s_] *                    \
                        Bsrc[(c_ * S + s_) * S + l_];                     \
            dst[(c_ * S + i_) * S + l_] = acc_;                          \
        } }                                                               \
} while (0)

__global__ __launch_bounds__(256) void hmm_setup(
    const float* __restrict__ usi,   // (16,8)
    const float* __restrict__ ucw,   // (500,8)
    const float* __restrict__ uem,   // (16,1500)
    const float* __restrict__ utm,   // (8,16,16)
    float* __restrict__ ws_lcw,      // (500,8)  log chain weights
    float* __restrict__ ws_pT,       // (8,16,16) prob-domain T
    float* __restrict__ ws_q,        // (20,8,16) chunk-start probs
    float* __restrict__ ws_emlse)    // (16)     emission LSE per state
{
    __shared__ float bufT[C * S * S];
    __shared__ float bufX[C * S * S];
    __shared__ float bufY[C * S * S];
    __shared__ float bufZ[C * S * S];
    __shared__ float qbuf[C * S];
    const int tid = threadIdx.x;

    // log_softmax chain weights over C per row t
    for (int t = tid; t < TT; t += 256) {
        float x[C]; float m = -1e30f;
#pragma unroll
        for (int cc = 0; cc < C; ++cc) { x[cc] = ucw[t * C + cc]; m = fmaxf(m, x[cc]); }
        float acc = 0.f;
#pragma unroll
        for (int cc = 0; cc < C; ++cc) acc += fexp2((x[cc] - m) * L2E);
        const float lse = m + flog2(acc) * LN2;
#pragma unroll
        for (int cc = 0; cc < C; ++cc) ws_lcw[t * C + cc] = x[cc] - lse;
    }

    // emission LSE per state: 16 groups of 16 lanes (max-free; |uem|~N(0,1))
    {
        const int row = tid >> 4;
        const int ln  = tid & 15;
        const float* rp = uem + row * NN;
        float a = 0.f;
        for (int n = ln; n < NN; n += 16) a += fexp2(rp[n] * L2E);
#pragma unroll
        for (int off = 8; off >= 1; off >>= 1) a += __shfl_xor(a, off);
        if (ln == 0) ws_emlse[row] = flog2(a) * LN2;
    }

    // softmax transition rows (over s'), PROB domain
    if (tid < SC) {
        float x[S]; float m = -1e30f;
#pragma unroll
        for (int k = 0; k < S; ++k) { x[k] = utm[tid * S + k]; m = fmaxf(m, x[k]); }
        float acc = 0.f; float e[S];
#pragma unroll
        for (int k = 0; k < S; ++k) { e[k] = fexp2((x[k] - m) * L2E); acc += e[k]; }
        const float inv = 1.f / acc;
#pragma unroll
        for (int k = 0; k < S; ++k) {
            const float v = e[k] * inv;
            bufT[tid * S + k] = v;
            ws_pT[tid * S + k] = v;
        }
    }

    // p0 = softmax over states per chain
    if (tid < C) {
        const int cc = tid;
        float x[S]; float m = -1e30f;
#pragma unroll
        for (int s0 = 0; s0 < S; ++s0) { x[s0] = usi[s0 * C + cc]; m = fmaxf(m, x[s0]); }
        float acc = 0.f; float e[S];
#pragma unroll
        for (int s0 = 0; s0 < S; ++s0) { e[s0] = fexp2((x[s0] - m) * L2E); acc += e[s0]; }
        const float inv = 1.f / acc;
#pragma unroll
        for (int s0 = 0; s0 < S; ++s0) {
            const float v = e[s0] * inv;
            qbuf[cc * S + s0] = v;
            ws_q[cc * S + s0] = v;
        }
    }

    // A = T^25 per chain
    MM(bufX, bufT, bufT);   // T^2
    MM(bufY, bufX, bufX);   // T^4
    MM(bufZ, bufY, bufY);   // T^8
    MM(bufX, bufZ, bufZ);   // T^16
    MM(bufY, bufX, bufZ);   // T^24
    MM(bufX, bufY, bufT);   // T^25
    __syncthreads();

    // chunk starts: q_k = q_{k-1} * A
    const int c5 = tid >> 4;
    const int l5 = tid & 15;
    float Acol[S];
    if (tid < 128) {
#pragma unroll
        for (int s0 = 0; s0 < S; ++s0) Acol[s0] = bufX[(c5 * S + s0) * S + l5];
    }
    for (int k = 1; k < NCHUNK; ++k) {
        float acc = 0.f;
        if (tid < 128) {
#pragma unroll
            for (int s0 = 0; s0 < S; ++s0) acc += qbuf[c5 * S + s0] * Acol[s0];
        }
        __syncthreads();
        if (tid < 128) {
            qbuf[c5 * S + l5] = acc;
            ws_q[k * SC + c5 * S + l5] = acc;
        }
        __syncthreads();
    }
}

// ---------------- Kernel 2: fused recursion + broadcast + LSE --------------
// One block per t; 512 threads. Wave 0 recomputes h_t from q_{t/25} via
// t%25 in-register steps, writes out3 + hc; all threads then stream the
// 768 KB t-slice of out2 sequentially with NT float4 stores; out1 folded in.
__global__ __launch_bounds__(512) void fused_bcast(
    const float* __restrict__ uem,     // (16,1500)
    const float* __restrict__ ws_lcw,  // (500,8)
    const float* __restrict__ ws_pT,   // (8,16,16)
    const float* __restrict__ ws_q,    // (20,8,16)
    const float* __restrict__ ws_emlse,// (16)
    float* __restrict__ out1,          // (500,1500)
    float* __restrict__ out2,          // (500,16,8,1500)
    float* __restrict__ out3)          // (500,16,8)
{
    const int t = blockIdx.x;
    const int tid = threadIdx.x;
    __shared__ float hc[SC];
    __shared__ float Ws[S];
    __shared__ float em[S];

    if (tid >= 64 && tid < 64 + S) em[tid - 64] = ws_emlse[tid - 64];

    if (tid < 64) {
        const int c = tid >> 3;
        const int j = tid & 7;
        float Ta[S], Tb[S];
#pragma unroll
        for (int s0 = 0; s0 < S; ++s0) {
            Ta[s0] = ws_pT[(c * S + s0) * S + j];
            Tb[s0] = ws_pT[(c * S + s0) * S + j + 8];
        }
        const int k = t / CHUNK;
        const int m = t - k * CHUNK;
        float pa = ws_q[k * SC + c * S + j];
        float pb = ws_q[k * SC + c * S + j + 8];
        const int base = c << 3;
        for (int i = 0; i < m; ++i) {
            float pv[S];
#pragma unroll
            for (int q = 0; q < 8; ++q) {
                pv[q]     = __shfl(pa, base + q);
                pv[q + 8] = __shfl(pb, base + q);
            }
            float a0 = 0.f, a1 = 0.f, a2 = 0.f, a3 = 0.f;
            float b0 = 0.f, b1 = 0.f, b2 = 0.f, b3 = 0.f;
#pragma unroll
            for (int s0 = 0; s0 < S; s0 += 4) {
                a0 = fmaf(pv[s0],     Ta[s0],     a0);
                a1 = fmaf(pv[s0 + 1], Ta[s0 + 1], a1);
                a2 = fmaf(pv[s0 + 2], Ta[s0 + 2], a2);
                a3 = fmaf(pv[s0 + 3], Ta[s0 + 3], a3);
                b0 = fmaf(pv[s0],     Tb[s0],     b0);
                b1 = fmaf(pv[s0 + 1], Tb[s0 + 1], b1);
                b2 = fmaf(pv[s0 + 2], Tb[s0 + 2], b2);
                b3 = fmaf(pv[s0 + 3], Tb[s0 + 3], b3);
            }
            pa = (a0 + a1) + (a2 + a3);
            pb = (b0 + b1) + (b2 + b3);
        }
        const float la = flog2(pa) * LN2;
        const float lb = flog2(pb) * LN2;
        out3[(size_t)t * SC + j * C + c]       = la;
        out3[(size_t)t * SC + (j + 8) * C + c] = lb;
        const float w = ws_lcw[t * C + c];
        hc[j * C + c]       = la + w;
        hc[(j + 8) * C + c] = lb + w;
    }
    __syncthreads();
    if (tid < S) {
        float mx = -1e30f;
#pragma unroll
        for (int cc = 0; cc < C; ++cc) mx = fmaxf(mx, hc[tid * C + cc]);
        float acc = 0.f;
#pragma unroll
        for (int cc = 0; cc < C; ++cc) acc += fexp2((hc[tid * C + cc] - mx) * L2E);
        Ws[tid] = mx + flog2(acc) * LN2;
    }
    __syncthreads();

    if (tid < NF4) {
        f4v acc1 = {0.f, 0.f, 0.f, 0.f};
        float* o2t = out2 + (size_t)t * SC * NN + tid * 4;
        for (int s0 = 0; s0 < S; ++s0) {
            f4v e = *(const f4v*)(uem + s0 * NN + tid * 4);
            const float el = em[s0];
            e -= el;
            const float w = Ws[s0];
            acc1.x += fexp2((e.x + w) * L2E);
            acc1.y += fexp2((e.y + w) * L2E);
            acc1.z += fexp2((e.z + w) * L2E);
            acc1.w += fexp2((e.w + w) * L2E);
            float* orow = o2t + (size_t)s0 * C * NN;
#pragma unroll
            for (int cc = 0; cc < C; ++cc) {
                const float hv = hc[s0 * C + cc];
                f4v v = e + hv;
                __builtin_nontemporal_store(v, (f4v*)(orow + (size_t)cc * NN));
            }
        }
        f4v r;
        r.x = flog2(acc1.x) * LN2;
        r.y = flog2(acc1.y) * LN2;
        r.z = flog2(acc1.z) * LN2;
        r.w = flog2(acc1.w) * LN2;
        *(f4v*)(out1 + (size_t)t * NN + tid * 4) = r;
    }
}

extern "C" void kernel_launch(void* const* d_in, const int* in_sizes, int n_in,
                              void* d_out, int out_size, void* d_ws, size_t ws_size,
                              hipStream_t stream)
{
    const float* usi = (const float*)d_in[0];   // (16,8)
    const float* ucw = (const float*)d_in[1];   // (500,8)
    const float* uem = (const float*)d_in[2];   // (16,1,1500)
    const float* utm = (const float*)d_in[3];   // (8,16,16)

    float* out  = (float*)d_out;
    float* out1 = out;                                   // 750000
    float* out2 = out + 750000;                          // 96000000
    float* out3 = out + 750000 + 96000000;               // 64000

    float* ws       = (float*)d_ws;
    float* ws_lcw   = ws;             // 4000
    float* ws_pT    = ws + 4000;      // 2048
    float* ws_q     = ws + 6048;      // 2560
    float* ws_emlse = ws + 8608;      // 16

    hmm_setup<<<1, 256, 0, stream>>>(usi, ucw, uem, utm, ws_lcw, ws_pT, ws_q, ws_emlse);
    fused_bcast<<<TT, 512, 0, stream>>>(uem, ws_lcw, ws_pT, ws_q, ws_emlse,
                                        out1, out2, out3);
}